// Round 7
// baseline (157467.261 us; speedup 1.0000x reference)
//
#include <hip/hip_runtime.h>
#include <math.h>

#define T_STEPS 2048
#define BATCH   32
#define IN_DIM  512
#define H_DIM   512
#define G4      2048
#define NWG     16
#define NTHR    512
#define GLS     132      // gates LDS row stride (floats), padded

typedef __attribute__((ext_vector_type(8))) short short8;
typedef __attribute__((ext_vector_type(4))) float f32x4;
typedef __attribute__((ext_vector_type(4))) unsigned u32x4;

__device__ inline unsigned short f2bf(float f) {
    unsigned u = __builtin_bit_cast(unsigned, f);
    unsigned r = (u + 0x7FFFu + ((u >> 16) & 1u)) >> 16;
    return (unsigned short)r;
}
__device__ inline unsigned pack2(float a, float b) {
    return (unsigned)f2bf(a) | ((unsigned)f2bf(b) << 16);
}
// fast device transcendentals: v_exp_f32 / v_rcp_f32 (~1-2 ulp, fine vs bf16 noise)
__device__ inline float fsigm(float x) {
    return __builtin_amdgcn_rcpf(1.f + __expf(-x));
}
__device__ inline float ftanh(float x) {
    return 1.f - 2.f * __builtin_amdgcn_rcpf(__expf(2.f * x) + 1.f);
}
__device__ inline float sigm(float v) { return 1.f / (1.f + expf(-v)); }  // fallback path

// 4 parallel IC-coherent 16B loads + drain (round-4 proven)
__device__ inline void ld4x_ic(const void* p0, const void* p1,
                               const void* p2, const void* p3,
                               u32x4& v0, u32x4& v1, u32x4& v2, u32x4& v3) {
    asm volatile(
        "global_load_dwordx4 %0, %4, off sc1\n\t"
        "global_load_dwordx4 %1, %5, off sc1\n\t"
        "global_load_dwordx4 %2, %6, off sc1\n\t"
        "global_load_dwordx4 %3, %7, off sc1\n\t"
        "s_waitcnt vmcnt(0)"
        : "=&v"(v0), "=&v"(v1), "=&v"(v2), "=&v"(v3)
        : "v"(p0), "v"(p1), "v"(p2), "v"(p3) : "memory");
}

// ---------------------------------------------------------------------------
// W [1024][2048] fp32 -> Wt [2048][1024] bf16 (transposed; k<512 = x-part)
// ---------------------------------------------------------------------------
__global__ __launch_bounds__(256) void wt_kernel(const float* __restrict__ W,
                                                 unsigned short* __restrict__ Wt) {
    __shared__ unsigned short tile[32][33];
    const int n0 = blockIdx.x << 5, k0 = blockIdx.y << 5;
    const int tx = threadIdx.x & 31, ty = threadIdx.x >> 5;
    #pragma unroll
    for (int r = 0; r < 32; r += 8)
        tile[ty + r][tx] = f2bf(W[(size_t)(k0 + ty + r) * G4 + n0 + tx]);
    __syncthreads();
    #pragma unroll
    for (int r = 0; r < 32; r += 8)
        Wt[(size_t)(n0 + ty + r) * 1024 + k0 + tx] = tile[tx][ty + r];
}

__global__ void init_h(const float* __restrict__ h0, unsigned short* __restrict__ hb) {
    int i = blockIdx.x * 256 + threadIdx.x;   // 16384 total
    hb[i] = f2bf(h0[i]);
}

// ---------------------------------------------------------------------------
// Phase 1: pre[m][col] = x[m][:] @ W[0:512][col] + bias[col], bf16 MFMA.
// M=65536, N=2048, K=512. BM=BN=64, BK=32, 4 waves (wave = mtile). (R2-proven)
// ---------------------------------------------------------------------------
__global__ __launch_bounds__(256) void xw_mfma(const float* __restrict__ x,
                                               const unsigned short* __restrict__ Wt,
                                               const float* __restrict__ bias,
                                               float* __restrict__ pre) {
    __shared__ unsigned short As[64][40];   // row stride 80B (16B-aligned)
    __shared__ unsigned short Bs[64][40];
    const int tid = threadIdx.x;
    const int w = tid >> 6, l = tid & 63;
    const int m0 = blockIdx.y << 6, n0 = blockIdx.x << 6;
    const int srow = tid >> 2, sseg = (tid & 3) << 3;
    const int arow = (w << 4) + (l & 15);
    const int kb = (l >> 4) << 3;
    f32x4 acc[4] = {};

    for (int kc = 0; kc < 16; ++kc) {
        const float* xs = x + (size_t)(m0 + srow) * IN_DIM + kc * 32 + sseg;
        float4 xa = *(const float4*)xs;
        float4 xb2 = *(const float4*)(xs + 4);
        int4 av;
        av.x = pack2(xa.x, xa.y);  av.y = pack2(xa.z, xa.w);
        av.z = pack2(xb2.x, xb2.y); av.w = pack2(xb2.z, xb2.w);
        *(int4*)&As[srow][sseg] = av;
        *(int4*)&Bs[srow][sseg] = *(const int4*)(Wt + (size_t)(n0 + srow) * 1024 + kc * 32 + sseg);
        __syncthreads();
        short8 af = *(const short8*)&As[arow][kb];
        #pragma unroll
        for (int n = 0; n < 4; ++n) {
            short8 bf = *(const short8*)&Bs[(n << 4) + (l & 15)][kb];
            acc[n] = __builtin_amdgcn_mfma_f32_16x16x32_bf16(af, bf, acc[n], 0, 0, 0);
        }
        __syncthreads();
    }
    #pragma unroll
    for (int n = 0; n < 4; ++n) {
        const int col = n0 + (n << 4) + (l & 15);
        const float bb = bias[col];
        #pragma unroll
        for (int ri = 0; ri < 4; ++ri) {
            const int row = m0 + (w << 4) + ((l >> 4) << 2) + ri;
            pre[(size_t)row * G4 + col] = acc[n][ri] + bb;
        }
    }
}

// ---------------------------------------------------------------------------
// Persistent scan: 16 WGs x 512 thr (8 waves). WG g owns hidden cols
// [g*32,(g+1)*32) -> 128 gate cols. W_h frags in VGPRs (64 regs); h staged
// per step into 32KB swizzled LDS via sc1; c in registers.
// Barrier v2: per-WG arrival slots (64B apart, contention-free atomicAdd)
// + 16-lane parallel sc1 poll. Fast v_exp/v_rcp gate math.
// ---------------------------------------------------------------------------
__global__ __launch_bounds__(NTHR, 1) void lstm_scan(
        const unsigned short* __restrict__ Wt,   // [2048][1024], h-part at k+512
        const float* __restrict__ pre,           // [65536][2048], bias included
        const float* __restrict__ c0,            // [32][512]
        unsigned short* __restrict__ hbuf,       // [2][32][512] bf16, [0] init'd
        float* __restrict__ outs,                // [2048][32][512]
        float* __restrict__ hf, float* __restrict__ cf,
        unsigned int* __restrict__ flags) {      // 16 slots, 64B apart
    __shared__ char Hl[32768];   // h: 32 rows x 1KB, swizzled; gates alias after MFMA

    const int g = blockIdx.x;
    const int tid = threadIdx.x;
    const int w = tid >> 6, l = tid & 63;

    // --- W_h fragments: wave w -> global gate cols gc (16 cols/wave)
    const int gc = ((w >> 1) << 9) + (g << 5) + ((w & 1) << 4) + (l & 15);
    const int ksub = (l >> 4) << 3;
    short8 wfh[16];
    #pragma unroll
    for (int kc = 0; kc < 16; ++kc)
        wfh[kc] = *(const short8*)(Wt + (size_t)gc * 1024 + 512 + kc * 32 + ksub);

    // --- update-phase mapping: thread -> (b, even col pair)
    const int b   = tid >> 4;
    const int hcp = (tid & 15) << 1;
    const int col = (g << 5) + hcp;
    float2 cv = *(const float2*)(c0 + (b << 9) + col);

    const int arow0 = l & 15, arow1 = (l & 15) + 16;
    const int kbyte = (l >> 4) << 4;
    const int swz0 = (arow0 & 7) << 4, swz1 = (arow1 & 7) << 4;
    const int lcw = (w << 4) + (l & 15);

    // --- stage h(0) -> Hl (IC loads; hbuf[0] written by init_h)
    {
        const unsigned short* hp0 = hbuf + (w << 9) + (l << 3);
        u32x4 v0, v1, v2, v3;
        ld4x_ic(hp0, hp0 + 4096, hp0 + 8192, hp0 + 12288, v0, v1, v2, v3);
        char* hd = Hl + w * 1024 + ((l << 4) ^ (w << 4));
        *(u32x4*)hd = v0; *(u32x4*)(hd + 8192) = v1;
        *(u32x4*)(hd + 16384) = v2; *(u32x4*)(hd + 24576) = v3;
    }
    __syncthreads();

    for (int gt = 0; gt < T_STEPS; ++gt) {
        // 1. this step's xW+bias (issued early, consumed in update phase)
        const float* pr = pre + ((size_t)gt * BATCH + b) * G4 + col;
        const float2 pf = *(const float2*)pr;
        const float2 pi = *(const float2*)(pr + 512);
        const float2 pg = *(const float2*)(pr + 1024);
        const float2 po = *(const float2*)(pr + 1536);

        // 2. MFMA: h[32,512] @ Wh[512,16/wave] -> gates
        f32x4 acc0 = {0.f, 0.f, 0.f, 0.f}, acc1 = {0.f, 0.f, 0.f, 0.f};
        #pragma unroll
        for (int kc = 0; kc < 16; ++kc) {
            const int kb2 = kc * 64 + kbyte;
            short8 ha0 = *(const short8*)(Hl + arow0 * 1024 + (kb2 ^ swz0));
            short8 ha1 = *(const short8*)(Hl + arow1 * 1024 + (kb2 ^ swz1));
            acc0 = __builtin_amdgcn_mfma_f32_16x16x32_bf16(ha0, wfh[kc], acc0, 0, 0, 0);
            acc1 = __builtin_amdgcn_mfma_f32_16x16x32_bf16(ha1, wfh[kc], acc1, 0, 0, 0);
        }
        __syncthreads();                 // everyone done reading Hl

        // 3. gates -> LDS (alias Hl region)
        float* Gl = (float*)Hl;
        #pragma unroll
        for (int ri = 0; ri < 4; ++ri) {
            const int br = ((l >> 4) << 2) + ri;
            Gl[br * GLS + lcw] = acc0[ri];
            Gl[(br + 16) * GLS + lcw] = acc1[ri];
        }
        __syncthreads();                 // gates visible

        // 4. elementwise update (fast transcendentals)
        const float* grow = Gl + b * GLS + hcp;
        const float f0 = fsigm(grow[0]  + pf.x), f1 = fsigm(grow[1]  + pf.y);
        const float i0 = fsigm(grow[32] + pi.x), i1 = fsigm(grow[33] + pi.y);
        const float g0 = ftanh(grow[64] + pg.x), g1 = ftanh(grow[65] + pg.y);
        const float o0 = fsigm(grow[96] + po.x), o1 = fsigm(grow[97] + po.y);
        cv.x = f0 * cv.x + i0 * g0;
        cv.y = f1 * cv.y + i1 * g1;
        const float hn0 = o0 * ftanh(cv.x);
        const float hn1 = o1 * ftanh(cv.y);

        // 5. stores: outs (plain), h for next step (IC-coherent)
        *(float2*)(outs + ((size_t)gt << 14) + (b << 9) + col) = make_float2(hn0, hn1);
        {
            unsigned* hdst = (unsigned*)hbuf + (((gt + 1) & 1) << 13) + (b << 8) + (col >> 1);
            const unsigned pk = pack2(hn0, hn1);
            asm volatile("global_store_dword %0, %1, off sc1" :: "v"(hdst), "v"(pk) : "memory");
        }
        if (gt == T_STEPS - 1) {
            *(float2*)(hf + (b << 9) + col) = make_float2(hn0, hn1);
            *(float2*)(cf + (b << 9) + col) = make_float2(cv.x, cv.y);
            break;                              // no final barrier needed
        }

        // 6. grid barrier v2: drain h stores; contention-free arrival to own
        //    64B slot; 16 lanes poll the 16 slots in parallel (sc1).
        asm volatile("s_waitcnt vmcnt(0)" ::: "memory");
        __syncthreads();
        if (tid == 0)
            atomicAdd(flags + (g << 4), 1u);    // slot value = steps completed
        if (tid < 16) {
            unsigned* slot = flags + (tid << 4);
            const unsigned tgt = (unsigned)(gt + 1);
            for (;;) {
                unsigned vb;
                asm volatile("global_load_dword %0, %1, off sc1\n\ts_waitcnt vmcnt(0)"
                             : "=v"(vb) : "v"(slot) : "memory");
                if (vb >= tgt) break;
                __builtin_amdgcn_s_sleep(1);
            }
        }
        __syncthreads();

        // 7. stage h(gt+1) -> Hl (IC-coherent)
        {
            const unsigned short* hsrc = hbuf + (((gt + 1) & 1) << 14) + (w << 9) + (l << 3);
            u32x4 v0, v1, v2, v3;
            ld4x_ic(hsrc, hsrc + 4096, hsrc + 8192, hsrc + 12288, v0, v1, v2, v3);
            char* hd = Hl + w * 1024 + ((l << 4) ^ (w << 4));
            *(u32x4*)hd = v0; *(u32x4*)(hd + 8192) = v1;
            *(u32x4*)(hd + 16384) = v2; *(u32x4*)(hd + 24576) = v3;
        }
        __syncthreads();                 // Hl ready
    }
}

// ---------------------------------------------------------------------------
// Minimal fallback (tiny ws): 2048 step launches, fp32, x folded in.
// ---------------------------------------------------------------------------
__global__ __launch_bounds__(256) void lstm_step(const float* __restrict__ x_t,
                                                 const float* __restrict__ h_prev,
                                                 const float* __restrict__ W,
                                                 const float* __restrict__ bias,
                                                 const float* __restrict__ c_in,
                                                 float* __restrict__ c_out,
                                                 float* __restrict__ h_out,
                                                 float* __restrict__ hf,
                                                 float* __restrict__ cf, int last) {
    const int tid = threadIdx.x;
    const int hcc = tid & 7, b = tid >> 3;
    const int col = blockIdx.x * 8 + hcc;
    float a0 = bias[col], a1 = bias[col + 512], a2 = bias[col + 1024], a3 = bias[col + 1536];
    const float* xr = x_t + (size_t)b * IN_DIM;
    const float* hr = h_prev + (size_t)b * H_DIM;
    for (int k = 0; k < IN_DIM; ++k) {
        const float v = xr[k];
        const float* wk = &W[(size_t)k * G4 + col];
        a0 += v * wk[0]; a1 += v * wk[512]; a2 += v * wk[1024]; a3 += v * wk[1536];
    }
    for (int k = 0; k < H_DIM; ++k) {
        const float v = hr[k];
        const float* wk = &W[(size_t)(512 + k) * G4 + col];
        a0 += v * wk[0]; a1 += v * wk[512]; a2 += v * wk[1024]; a3 += v * wk[1536];
    }
    const float cn = sigm(a0) * c_in[(size_t)b * H_DIM + col] + sigm(a1) * tanhf(a2);
    const float hn = sigm(a3) * tanhf(cn);
    c_out[(size_t)b * H_DIM + col] = cn;
    h_out[(size_t)b * H_DIM + col] = hn;
    if (last) { hf[(size_t)b * H_DIM + col] = hn; cf[(size_t)b * H_DIM + col] = cn; }
}

extern "C" void kernel_launch(void* const* d_in, const int* in_sizes, int n_in,
                              void* d_out, int out_size, void* d_ws, size_t ws_size,
                              hipStream_t stream) {
    const float* x    = (const float*)d_in[0];
    const float* h0   = (const float*)d_in[1];
    const float* c0   = (const float*)d_in[2];
    const float* W    = (const float*)d_in[3];
    const float* bias = (const float*)d_in[4];

    float* outs = (float*)d_out;
    float* hf   = outs + (size_t)T_STEPS * BATCH * H_DIM;
    float* cf   = hf + BATCH * H_DIM;

    const size_t OFF_WT = 536870912ull;           // pre: 512 MB @ 0
    const size_t OFF_HB = OFF_WT + 4194304ull;    // Wt: 4 MB
    const size_t OFF_FL = OFF_HB + 65536ull;      // hbuf: 64 KB
    const size_t NEED   = OFF_FL + 4096ull;       // ~516.2 MB (< 536.9 MB proven)

    if (ws_size >= NEED) {
        float* pre         = (float*)d_ws;
        unsigned short* Wt = (unsigned short*)((char*)d_ws + OFF_WT);
        unsigned short* hb = (unsigned short*)((char*)d_ws + OFF_HB);
        unsigned int* flags = (unsigned int*)((char*)d_ws + OFF_FL);

        hipMemsetAsync(flags, 0, 4096, stream);
        wt_kernel<<<dim3(64, 32), 256, 0, stream>>>(W, Wt);
        init_h<<<64, 256, 0, stream>>>(h0, hb);
        xw_mfma<<<dim3(32, 1024), 256, 0, stream>>>(x, Wt, bias, pre);
        lstm_scan<<<NWG, NTHR, 0, stream>>>(Wt, pre, c0, hb, outs, hf, cf, flags);
    } else {
        float* c_ws = (float*)d_ws;
        for (int t = 0; t < T_STEPS; ++t) {
            const float* hp = t ? outs + (size_t)(t - 1) * BATCH * H_DIM : h0;
            const float* ci = t ? c_ws : c0;
            lstm_step<<<64, 256, 0, stream>>>(x + (size_t)t * BATCH * IN_DIM,
                                              hp, W, bias, ci, c_ws,
                                              outs + (size_t)t * BATCH * H_DIM,
                                              hf, cf, (t == T_STEPS - 1) ? 1 : 0);
        }
    }
}

// Round 8
// 7684.627 us; speedup vs baseline: 20.4912x; 20.4912x over previous
//
#include <hip/hip_runtime.h>
#include <math.h>

#define T_STEPS 2048
#define BATCH   32
#define IN_DIM  512
#define H_DIM   512
#define G4      2048
#define NWG     16
#define NTHR    512
#define TC      512      // scan steps per chunk
#define NCHUNK  4
#define GLS     132      // gates LDS row stride (floats), padded

typedef __attribute__((ext_vector_type(8))) short short8;
typedef __attribute__((ext_vector_type(4))) float f32x4;
typedef __attribute__((ext_vector_type(4))) unsigned u32x4;

__device__ inline unsigned short f2bf(float f) {
    unsigned u = __builtin_bit_cast(unsigned, f);
    unsigned r = (u + 0x7FFFu + ((u >> 16) & 1u)) >> 16;
    return (unsigned short)r;
}
__device__ inline unsigned pack2(float a, float b) {
    return (unsigned)f2bf(a) | ((unsigned)f2bf(b) << 16);
}
// fast transcendentals: v_exp_f32 / v_rcp_f32 (~2 ulp; bf16 noise dominates)
__device__ inline float fsigm(float x) {
    return __builtin_amdgcn_rcpf(1.f + __expf(-x));
}
__device__ inline float ftanh(float x) {
    return 1.f - 2.f * __builtin_amdgcn_rcpf(__expf(2.f * x) + 1.f);
}
__device__ inline float sigm(float v) { return 1.f / (1.f + expf(-v)); }  // fallback

// 4 parallel IC-coherent 16B loads + drain (round-4 proven)
__device__ inline void ld4x_ic(const void* p0, const void* p1,
                               const void* p2, const void* p3,
                               u32x4& v0, u32x4& v1, u32x4& v2, u32x4& v3) {
    asm volatile(
        "global_load_dwordx4 %0, %4, off sc1\n\t"
        "global_load_dwordx4 %1, %5, off sc1\n\t"
        "global_load_dwordx4 %2, %6, off sc1\n\t"
        "global_load_dwordx4 %3, %7, off sc1\n\t"
        "s_waitcnt vmcnt(0)"
        : "=&v"(v0), "=&v"(v1), "=&v"(v2), "=&v"(v3)
        : "v"(p0), "v"(p1), "v"(p2), "v"(p3) : "memory");
}

// ---------------------------------------------------------------------------
// W [1024][2048] fp32 -> Wt [2048][1024] bf16 (transposed; k<512 = x-part)
// ---------------------------------------------------------------------------
__global__ __launch_bounds__(256) void wt_kernel(const float* __restrict__ W,
                                                 unsigned short* __restrict__ Wt) {
    __shared__ unsigned short tile[32][33];
    const int n0 = blockIdx.x << 5, k0 = blockIdx.y << 5;
    const int tx = threadIdx.x & 31, ty = threadIdx.x >> 5;
    #pragma unroll
    for (int r = 0; r < 32; r += 8)
        tile[ty + r][tx] = f2bf(W[(size_t)(k0 + ty + r) * G4 + n0 + tx]);
    __syncthreads();
    #pragma unroll
    for (int r = 0; r < 32; r += 8)
        Wt[(size_t)(n0 + ty + r) * 1024 + k0 + tx] = tile[tx][ty + r];
}

__global__ void init_h(const float* __restrict__ h0, unsigned short* __restrict__ hb) {
    int i = blockIdx.x * 256 + threadIdx.x;   // 16384 total
    hb[i] = f2bf(h0[i]);
}

// ---------------------------------------------------------------------------
// Phase 1 (per chunk): pre[m][col] = x[m][:] @ W[0:512][col] + bias[col].
// M=TC*32=16384, N=2048, K=512. BM=BN=64, BK=32, 4 waves. (R2/R4-proven)
// ---------------------------------------------------------------------------
__global__ __launch_bounds__(256) void xw_mfma(const float* __restrict__ x,
                                               const unsigned short* __restrict__ Wt,
                                               const float* __restrict__ bias,
                                               float* __restrict__ pre) {
    __shared__ unsigned short As[64][40];   // row stride 80B (16B-aligned)
    __shared__ unsigned short Bs[64][40];
    const int tid = threadIdx.x;
    const int w = tid >> 6, l = tid & 63;
    const int m0 = blockIdx.y << 6, n0 = blockIdx.x << 6;
    const int srow = tid >> 2, sseg = (tid & 3) << 3;
    const int arow = (w << 4) + (l & 15);
    const int kb = (l >> 4) << 3;
    f32x4 acc[4] = {};

    for (int kc = 0; kc < 16; ++kc) {
        const float* xs = x + (size_t)(m0 + srow) * IN_DIM + kc * 32 + sseg;
        float4 xa = *(const float4*)xs;
        float4 xb2 = *(const float4*)(xs + 4);
        int4 av;
        av.x = pack2(xa.x, xa.y);  av.y = pack2(xa.z, xa.w);
        av.z = pack2(xb2.x, xb2.y); av.w = pack2(xb2.z, xb2.w);
        *(int4*)&As[srow][sseg] = av;
        *(int4*)&Bs[srow][sseg] = *(const int4*)(Wt + (size_t)(n0 + srow) * 1024 + kc * 32 + sseg);
        __syncthreads();
        short8 af = *(const short8*)&As[arow][kb];
        #pragma unroll
        for (int n = 0; n < 4; ++n) {
            short8 bf = *(const short8*)&Bs[(n << 4) + (l & 15)][kb];
            acc[n] = __builtin_amdgcn_mfma_f32_16x16x32_bf16(af, bf, acc[n], 0, 0, 0);
        }
        __syncthreads();
    }
    #pragma unroll
    for (int n = 0; n < 4; ++n) {
        const int col = n0 + (n << 4) + (l & 15);
        const float bb = bias[col];
        #pragma unroll
        for (int ri = 0; ri < 4; ++ri) {
            const int row = m0 + (w << 4) + ((l >> 4) << 2) + ri;
            pre[(size_t)row * G4 + col] = acc[n][ri] + bb;
        }
    }
}

// ---------------------------------------------------------------------------
// Persistent scan (per chunk): 16 WGs x 512 thr (8 waves). WG g owns hidden
// cols [g*32,(g+1)*32) -> 128 gate cols. W_h frags in VGPRs; h via sc1 IC
// exchange (R4-proven); c in regs across chunk; barrier = per-WG slots
// (contention-free arrival) + 16-lane parallel sc1 poll; pre prefetched one
// step ahead so its HBM latency drains inside the barrier's vmcnt(0).
// ---------------------------------------------------------------------------
__global__ __launch_bounds__(NTHR, 1) void lstm_scan(
        const unsigned short* __restrict__ Wt,   // [2048][1024], h-part at k+512
        const float* __restrict__ pre,           // chunk: [TC*32][2048], bias incl.
        const float* __restrict__ cin,           // [32][512] fp32
        float* __restrict__ cout,                // [32][512] fp32
        unsigned short* __restrict__ hbuf,       // [2][32][512] bf16
        float* __restrict__ outs,                // [2048][32][512] (full)
        float* __restrict__ hf, float* __restrict__ cf,
        unsigned int* __restrict__ flags,        // 16 slots, 64B apart, monotonic
        int gt0) {
    __shared__ char Hl[32768];   // h: 32 rows x 1KB, swizzled; gates alias after MFMA

    const int g = blockIdx.x;
    const int tid = threadIdx.x;
    const int w = tid >> 6, l = tid & 63;

    // --- W_h fragments: wave w -> global gate cols gc (16 cols/wave)
    const int gc = ((w >> 1) << 9) + (g << 5) + ((w & 1) << 4) + (l & 15);
    const int ksub = (l >> 4) << 3;
    short8 wfh[16];
    #pragma unroll
    for (int kc = 0; kc < 16; ++kc)
        wfh[kc] = *(const short8*)(Wt + (size_t)gc * 1024 + 512 + kc * 32 + ksub);

    // --- update-phase mapping: thread -> (b, even col pair)
    const int b   = tid >> 4;
    const int hcp = (tid & 15) << 1;
    const int col = (g << 5) + hcp;
    float2 cv = *(const float2*)(cin + (b << 9) + col);

    const int arow0 = l & 15, arow1 = (l & 15) + 16;
    const int kbyte = (l >> 4) << 4;
    const int swz0 = (arow0 & 7) << 4, swz1 = (arow1 & 7) << 4;
    const int lcw = (w << 4) + (l & 15);

    // --- stage h(gt0) -> Hl (IC loads)
    {
        const unsigned short* hp0 = hbuf + ((gt0 & 1) << 14) + (w << 9) + (l << 3);
        u32x4 v0, v1, v2, v3;
        ld4x_ic(hp0, hp0 + 4096, hp0 + 8192, hp0 + 12288, v0, v1, v2, v3);
        char* hd = Hl + w * 1024 + ((l << 4) ^ (w << 4));
        *(u32x4*)hd = v0; *(u32x4*)(hd + 8192) = v1;
        *(u32x4*)(hd + 16384) = v2; *(u32x4*)(hd + 24576) = v3;
    }
    __syncthreads();

    // --- initial pre prefetch (t=0)
    const float* pr0 = pre + (size_t)b * G4 + col;
    float2 pf = *(const float2*)pr0;
    float2 pi = *(const float2*)(pr0 + 512);
    float2 pg = *(const float2*)(pr0 + 1024);
    float2 po = *(const float2*)(pr0 + 1536);

    for (int t = 0; t < TC; ++t) {
        const int gt = gt0 + t;

        // 1. MFMA: h[32,512] @ Wh[512,16/wave] -> gates
        f32x4 acc0 = {0.f, 0.f, 0.f, 0.f}, acc1 = {0.f, 0.f, 0.f, 0.f};
        #pragma unroll
        for (int kc = 0; kc < 16; ++kc) {
            const int kb2 = kc * 64 + kbyte;
            short8 ha0 = *(const short8*)(Hl + arow0 * 1024 + (kb2 ^ swz0));
            short8 ha1 = *(const short8*)(Hl + arow1 * 1024 + (kb2 ^ swz1));
            acc0 = __builtin_amdgcn_mfma_f32_16x16x32_bf16(ha0, wfh[kc], acc0, 0, 0, 0);
            acc1 = __builtin_amdgcn_mfma_f32_16x16x32_bf16(ha1, wfh[kc], acc1, 0, 0, 0);
        }
        __syncthreads();                 // everyone done reading Hl

        // 2. gates -> LDS (alias Hl region)
        float* Gl = (float*)Hl;
        #pragma unroll
        for (int ri = 0; ri < 4; ++ri) {
            const int br = ((l >> 4) << 2) + ri;
            Gl[br * GLS + lcw] = acc0[ri];
            Gl[(br + 16) * GLS + lcw] = acc1[ri];
        }
        __syncthreads();                 // gates visible

        // 3. issue pre prefetch for t+1 (consumed next iteration; completes
        //    inside this step's barrier vmcnt(0))
        const int tn = (t + 1 < TC) ? t + 1 : t;
        const float* prn = pre + ((size_t)tn * BATCH + b) * G4 + col;
        const float2 npf = *(const float2*)prn;
        const float2 npi = *(const float2*)(prn + 512);
        const float2 npg = *(const float2*)(prn + 1024);
        const float2 npo = *(const float2*)(prn + 1536);

        // 4. elementwise update (fast transcendentals, pre from prefetch regs)
        const float* grow = Gl + b * GLS + hcp;
        const float f0 = fsigm(grow[0]  + pf.x), f1 = fsigm(grow[1]  + pf.y);
        const float i0 = fsigm(grow[32] + pi.x), i1 = fsigm(grow[33] + pi.y);
        const float g0 = ftanh(grow[64] + pg.x), g1 = ftanh(grow[65] + pg.y);
        const float o0 = fsigm(grow[96] + po.x), o1 = fsigm(grow[97] + po.y);
        cv.x = f0 * cv.x + i0 * g0;
        cv.y = f1 * cv.y + i1 * g1;
        const float hn0 = o0 * ftanh(cv.x);
        const float hn1 = o1 * ftanh(cv.y);
        pf = npf; pi = npi; pg = npg; po = npo;

        // 5. stores: outs (plain), h for next step (IC-coherent)
        *(float2*)(outs + ((size_t)gt << 14) + (b << 9) + col) = make_float2(hn0, hn1);
        {
            unsigned* hdst = (unsigned*)hbuf + (((gt + 1) & 1) << 13) + (b << 8) + (col >> 1);
            const unsigned pk = pack2(hn0, hn1);
            asm volatile("global_store_dword %0, %1, off sc1" :: "v"(hdst), "v"(pk) : "memory");
        }
        if (gt == T_STEPS - 1) {
            *(float2*)(hf + (b << 9) + col) = make_float2(hn0, hn1);
            *(float2*)(cf + (b << 9) + col) = make_float2(cv.x, cv.y);
            break;                              // no final barrier needed
        }

        // 6. grid barrier: drain stores; contention-free arrival to own 64B
        //    slot; 16 lanes poll the 16 slots in parallel (sc1).
        asm volatile("s_waitcnt vmcnt(0)" ::: "memory");
        __syncthreads();
        if (tid == 0)
            atomicAdd(flags + (g << 4), 1u);    // slot value = global steps done
        if (tid < 16) {
            unsigned* slot = flags + (tid << 4);
            const unsigned tgt = (unsigned)(gt + 1);
            for (;;) {
                unsigned vb;
                asm volatile("global_load_dword %0, %1, off sc1\n\ts_waitcnt vmcnt(0)"
                             : "=v"(vb) : "v"(slot) : "memory");
                if (vb >= tgt) break;
                __builtin_amdgcn_s_sleep(1);
            }
        }
        __syncthreads();

        // 7. stage h(gt+1) -> Hl (IC-coherent)
        {
            const unsigned short* hsrc = hbuf + (((gt + 1) & 1) << 14) + (w << 9) + (l << 3);
            u32x4 v0, v1, v2, v3;
            ld4x_ic(hsrc, hsrc + 4096, hsrc + 8192, hsrc + 12288, v0, v1, v2, v3);
            char* hd = Hl + w * 1024 + ((l << 4) ^ (w << 4));
            *(u32x4*)hd = v0; *(u32x4*)(hd + 8192) = v1;
            *(u32x4*)(hd + 16384) = v2; *(u32x4*)(hd + 24576) = v3;
        }
        __syncthreads();                 // Hl ready
    }

    cout[(b << 9) + col]     = cv.x;
    cout[(b << 9) + col + 1] = cv.y;
}

// ---------------------------------------------------------------------------
// Minimal fallback (tiny ws): 2048 step launches, fp32, x folded in.
// ---------------------------------------------------------------------------
__global__ __launch_bounds__(256) void lstm_step(const float* __restrict__ x_t,
                                                 const float* __restrict__ h_prev,
                                                 const float* __restrict__ W,
                                                 const float* __restrict__ bias,
                                                 const float* __restrict__ c_in,
                                                 float* __restrict__ c_out,
                                                 float* __restrict__ h_out,
                                                 float* __restrict__ hf,
                                                 float* __restrict__ cf, int last) {
    const int tid = threadIdx.x;
    const int hcc = tid & 7, b = tid >> 3;
    const int col = blockIdx.x * 8 + hcc;
    float a0 = bias[col], a1 = bias[col + 512], a2 = bias[col + 1024], a3 = bias[col + 1536];
    const float* xr = x_t + (size_t)b * IN_DIM;
    const float* hr = h_prev + (size_t)b * H_DIM;
    for (int k = 0; k < IN_DIM; ++k) {
        const float v = xr[k];
        const float* wk = &W[(size_t)k * G4 + col];
        a0 += v * wk[0]; a1 += v * wk[512]; a2 += v * wk[1024]; a3 += v * wk[1536];
    }
    for (int k = 0; k < H_DIM; ++k) {
        const float v = hr[k];
        const float* wk = &W[(size_t)(512 + k) * G4 + col];
        a0 += v * wk[0]; a1 += v * wk[512]; a2 += v * wk[1024]; a3 += v * wk[1536];
    }
    const float cn = sigm(a0) * c_in[(size_t)b * H_DIM + col] + sigm(a1) * tanhf(a2);
    const float hn = sigm(a3) * tanhf(cn);
    c_out[(size_t)b * H_DIM + col] = cn;
    h_out[(size_t)b * H_DIM + col] = hn;
    if (last) { hf[(size_t)b * H_DIM + col] = hn; cf[(size_t)b * H_DIM + col] = cn; }
}

extern "C" void kernel_launch(void* const* d_in, const int* in_sizes, int n_in,
                              void* d_out, int out_size, void* d_ws, size_t ws_size,
                              hipStream_t stream) {
    const float* x    = (const float*)d_in[0];
    const float* h0   = (const float*)d_in[1];
    const float* c0   = (const float*)d_in[2];
    const float* W    = (const float*)d_in[3];
    const float* bias = (const float*)d_in[4];

    float* outs = (float*)d_out;
    float* hf   = outs + (size_t)T_STEPS * BATCH * H_DIM;
    float* cf   = hf + BATCH * H_DIM;

    // PROVEN-FIT layout (ran in rounds 3 and 4): 138,481,664 bytes total.
    const size_t OFF_WT = 134217728ull;            // pre chunk: 128 MB @ 0
    const size_t OFF_HB = OFF_WT + 4194304ull;     // Wt: 4 MB
    const size_t OFF_C  = OFF_HB + 65536ull;       // hbuf: 64 KB
    const size_t OFF_FL = OFF_C + 65536ull;        // c: 64 KB
    const size_t NEED   = OFF_FL + 4096ull;

    if (ws_size >= NEED) {
        float* pre          = (float*)d_ws;
        unsigned short* Wt  = (unsigned short*)((char*)d_ws + OFF_WT);
        unsigned short* hb  = (unsigned short*)((char*)d_ws + OFF_HB);
        float* c_ws         = (float*)((char*)d_ws + OFF_C);
        unsigned int* flags = (unsigned int*)((char*)d_ws + OFF_FL);

        hipMemsetAsync(flags, 0, 4096, stream);
        wt_kernel<<<dim3(64, 32), 256, 0, stream>>>(W, Wt);
        init_h<<<64, 256, 0, stream>>>(h0, hb);
        for (int k = 0; k < NCHUNK; ++k) {
            xw_mfma<<<dim3(32, TC * BATCH / 64), 256, 0, stream>>>(
                x + (size_t)k * TC * BATCH * IN_DIM, Wt, bias, pre);
            lstm_scan<<<NWG, NTHR, 0, stream>>>(
                Wt, pre, (k == 0) ? c0 : c_ws, c_ws, hb, outs, hf, cf, flags, k * TC);
        }
    } else {
        float* c_ws = (float*)d_ws;
        for (int t = 0; t < T_STEPS; ++t) {
            const float* hp = t ? outs + (size_t)(t - 1) * BATCH * H_DIM : h0;
            const float* ci = t ? c_ws : c0;
            lstm_step<<<64, 256, 0, stream>>>(x + (size_t)t * BATCH * IN_DIM,
                                              hp, W, bias, ci, c_ws,
                                              outs + (size_t)t * BATCH * H_DIM,
                                              hf, cf, (t == T_STEPS - 1) ? 1 : 0);
        }
    }
}

// Round 9
// 7483.244 us; speedup vs baseline: 21.0426x; 1.0269x over previous
//
#include <hip/hip_runtime.h>
#include <math.h>

#define T_STEPS 2048
#define BATCH   32
#define IN_DIM  512
#define H_DIM   512
#define G4      2048
#define NWG     16
#define NTHR    512
#define TC      512      // scan steps per chunk
#define NCHUNK  4
#define GLS     132      // gates LDS row stride (floats), padded

typedef __attribute__((ext_vector_type(8))) short short8;
typedef __attribute__((ext_vector_type(4))) float f32x4;
typedef __attribute__((ext_vector_type(2))) float f32x2;
typedef __attribute__((ext_vector_type(4))) unsigned u32x4;

__device__ inline unsigned short f2bf(float f) {
    unsigned u = __builtin_bit_cast(unsigned, f);
    unsigned r = (u + 0x7FFFu + ((u >> 16) & 1u)) >> 16;
    return (unsigned short)r;
}
__device__ inline unsigned pack2(float a, float b) {
    return (unsigned)f2bf(a) | ((unsigned)f2bf(b) << 16);
}
// fast transcendentals: v_exp_f32 / v_rcp_f32 (~2 ulp; bf16 noise dominates)
__device__ inline float fsigm(float x) {
    return __builtin_amdgcn_rcpf(1.f + __expf(-x));
}
__device__ inline float ftanh(float x) {
    return 1.f - 2.f * __builtin_amdgcn_rcpf(__expf(2.f * x) + 1.f);
}
__device__ inline float sigm(float v) { return 1.f / (1.f + expf(-v)); }  // fallback

// 4 parallel IC-coherent 16B loads + drain (round-4 proven)
__device__ inline void ld4x_ic(const void* p0, const void* p1,
                               const void* p2, const void* p3,
                               u32x4& v0, u32x4& v1, u32x4& v2, u32x4& v3) {
    asm volatile(
        "global_load_dwordx4 %0, %4, off sc1\n\t"
        "global_load_dwordx4 %1, %5, off sc1\n\t"
        "global_load_dwordx4 %2, %6, off sc1\n\t"
        "global_load_dwordx4 %3, %7, off sc1\n\t"
        "s_waitcnt vmcnt(0)"
        : "=&v"(v0), "=&v"(v1), "=&v"(v2), "=&v"(v3)
        : "v"(p0), "v"(p1), "v"(p2), "v"(p3) : "memory");
}

// ---------------------------------------------------------------------------
// W [1024][2048] fp32 -> Wt [2048][1024] bf16 (transposed; k<512 = x-part)
// ---------------------------------------------------------------------------
__global__ __launch_bounds__(256) void wt_kernel(const float* __restrict__ W,
                                                 unsigned short* __restrict__ Wt) {
    __shared__ unsigned short tile[32][33];
    const int n0 = blockIdx.x << 5, k0 = blockIdx.y << 5;
    const int tx = threadIdx.x & 31, ty = threadIdx.x >> 5;
    #pragma unroll
    for (int r = 0; r < 32; r += 8)
        tile[ty + r][tx] = f2bf(W[(size_t)(k0 + ty + r) * G4 + n0 + tx]);
    __syncthreads();
    #pragma unroll
    for (int r = 0; r < 32; r += 8)
        Wt[(size_t)(n0 + ty + r) * 1024 + k0 + tx] = tile[tx][ty + r];
}

__global__ void init_h(const float* __restrict__ h0, unsigned short* __restrict__ hb) {
    int i = blockIdx.x * 256 + threadIdx.x;   // 16384 total
    hb[i] = f2bf(h0[i]);
}

// ---------------------------------------------------------------------------
// Phase 1 (per chunk): pre[m][col] = x[m][:] @ W[0:512][col] + bias[col].
// M=TC*32=16384, N=2048, K=512. BM=BN=64, BK=32, 4 waves. (R2/R4/R8-proven)
// ---------------------------------------------------------------------------
__global__ __launch_bounds__(256) void xw_mfma(const float* __restrict__ x,
                                               const unsigned short* __restrict__ Wt,
                                               const float* __restrict__ bias,
                                               float* __restrict__ pre) {
    __shared__ unsigned short As[64][40];   // row stride 80B (16B-aligned)
    __shared__ unsigned short Bs[64][40];
    const int tid = threadIdx.x;
    const int w = tid >> 6, l = tid & 63;
    const int m0 = blockIdx.y << 6, n0 = blockIdx.x << 6;
    const int srow = tid >> 2, sseg = (tid & 3) << 3;
    const int arow = (w << 4) + (l & 15);
    const int kb = (l >> 4) << 3;
    f32x4 acc[4] = {};

    for (int kc = 0; kc < 16; ++kc) {
        const float* xs = x + (size_t)(m0 + srow) * IN_DIM + kc * 32 + sseg;
        float4 xa = *(const float4*)xs;
        float4 xb2 = *(const float4*)(xs + 4);
        int4 av;
        av.x = pack2(xa.x, xa.y);  av.y = pack2(xa.z, xa.w);
        av.z = pack2(xb2.x, xb2.y); av.w = pack2(xb2.z, xb2.w);
        *(int4*)&As[srow][sseg] = av;
        *(int4*)&Bs[srow][sseg] = *(const int4*)(Wt + (size_t)(n0 + srow) * 1024 + kc * 32 + sseg);
        __syncthreads();
        short8 af = *(const short8*)&As[arow][kb];
        #pragma unroll
        for (int n = 0; n < 4; ++n) {
            short8 bf = *(const short8*)&Bs[(n << 4) + (l & 15)][kb];
            acc[n] = __builtin_amdgcn_mfma_f32_16x16x32_bf16(af, bf, acc[n], 0, 0, 0);
        }
        __syncthreads();
    }
    #pragma unroll
    for (int n = 0; n < 4; ++n) {
        const int col = n0 + (n << 4) + (l & 15);
        const float bb = bias[col];
        #pragma unroll
        for (int ri = 0; ri < 4; ++ri) {
            const int row = m0 + (w << 4) + ((l >> 4) << 2) + ri;
            pre[(size_t)row * G4 + col] = acc[n][ri] + bb;
        }
    }
}

// ---------------------------------------------------------------------------
// Persistent scan (per chunk): 16 WGs x 512 thr (8 waves). WG g owns hidden
// cols [g*32,(g+1)*32) -> 128 gate cols. W_h frags in VGPRs; h via sc1 IC
// exchange; barrier = R8's per-WG slots + 16-lane sc1 poll (tight).
// R9 deltas: (1) gates in separate LDS region (no Hl alias) -> 4 syncs/step;
// (2) all critical-window vmem in asm: stores then pre-loads then
// s_waitcnt vmcnt(4) so the barrier drains ONLY the 2 stores; pre loads ride
// through the barrier and are consumed after a vmcnt(0) next iteration.
// ---------------------------------------------------------------------------
__global__ __launch_bounds__(NTHR, 1) void lstm_scan(
        const unsigned short* __restrict__ Wt,   // [2048][1024], h-part at k+512
        const float* __restrict__ pre,           // chunk: [TC*32][2048], bias incl.
        const float* __restrict__ cin,           // [32][512] fp32
        float* __restrict__ cout,                // [32][512] fp32
        unsigned short* __restrict__ hbuf,       // [2][32][512] bf16
        float* __restrict__ outs,                // [2048][32][512] (full)
        float* __restrict__ hf, float* __restrict__ cf,
        unsigned int* __restrict__ flags,        // 16 slots, 64B apart, monotonic
        int gt0) {
    __shared__ char Hl[32768];        // h: 32 rows x 1KB, swizzled
    __shared__ float Gl[32 * GLS];    // gates: separate region (16.9KB)

    const int g = blockIdx.x;
    const int tid = threadIdx.x;
    const int w = tid >> 6, l = tid & 63;

    // --- W_h fragments: wave w -> global gate cols gc (16 cols/wave)
    const int gc = ((w >> 1) << 9) + (g << 5) + ((w & 1) << 4) + (l & 15);
    const int ksub = (l >> 4) << 3;
    short8 wfh[16];
    #pragma unroll
    for (int kc = 0; kc < 16; ++kc)
        wfh[kc] = *(const short8*)(Wt + (size_t)gc * 1024 + 512 + kc * 32 + ksub);

    // --- update-phase mapping: thread -> (b, even col pair)
    const int b   = tid >> 4;
    const int hcp = (tid & 15) << 1;
    const int col = (g << 5) + hcp;
    float2 cv = *(const float2*)(cin + (b << 9) + col);

    const int arow0 = l & 15, arow1 = (l & 15) + 16;
    const int kbyte = (l >> 4) << 4;
    const int swz0 = (arow0 & 7) << 4, swz1 = (arow1 & 7) << 4;
    const int lcw = (w << 4) + (l & 15);

    // --- stage h(gt0) -> Hl (IC loads)
    {
        const unsigned short* hp0 = hbuf + ((gt0 & 1) << 14) + (w << 9) + (l << 3);
        u32x4 v0, v1, v2, v3;
        ld4x_ic(hp0, hp0 + 4096, hp0 + 8192, hp0 + 12288, v0, v1, v2, v3);
        char* hd = Hl + w * 1024 + ((l << 4) ^ (w << 4));
        *(u32x4*)hd = v0; *(u32x4*)(hd + 8192) = v1;
        *(u32x4*)(hd + 16384) = v2; *(u32x4*)(hd + 24576) = v3;
    }
    __syncthreads();

    // --- initial pre prefetch for t=0 (asm loads; waited at first update)
    f32x2 pf, pi, pg, po;
    {
        const float* pr0 = pre + (size_t)b * G4 + col;
        asm volatile("global_load_dwordx2 %0, %1, off" : "=v"(pf) : "v"(pr0) : "memory");
        asm volatile("global_load_dwordx2 %0, %1, off" : "=v"(pi) : "v"(pr0 + 512) : "memory");
        asm volatile("global_load_dwordx2 %0, %1, off" : "=v"(pg) : "v"(pr0 + 1024) : "memory");
        asm volatile("global_load_dwordx2 %0, %1, off" : "=v"(po) : "v"(pr0 + 1536) : "memory");
    }

    for (int t = 0; t < TC; ++t) {
        const int gt = gt0 + t;

        // A. MFMA: h[32,512] @ Wh[512,16/wave] -> gates
        f32x4 acc0 = {0.f, 0.f, 0.f, 0.f}, acc1 = {0.f, 0.f, 0.f, 0.f};
        #pragma unroll
        for (int kc = 0; kc < 16; ++kc) {
            const int kb2 = kc * 64 + kbyte;
            short8 ha0 = *(const short8*)(Hl + arow0 * 1024 + (kb2 ^ swz0));
            short8 ha1 = *(const short8*)(Hl + arow1 * 1024 + (kb2 ^ swz1));
            acc0 = __builtin_amdgcn_mfma_f32_16x16x32_bf16(ha0, wfh[kc], acc0, 0, 0, 0);
            acc1 = __builtin_amdgcn_mfma_f32_16x16x32_bf16(ha1, wfh[kc], acc1, 0, 0, 0);
        }

        // B. gates -> Gl (separate region: no pre-write sync needed)
        #pragma unroll
        for (int ri = 0; ri < 4; ++ri) {
            const int br = ((l >> 4) << 2) + ri;
            Gl[br * GLS + lcw] = acc0[ri];
            Gl[(br + 16) * GLS + lcw] = acc1[ri];
        }
        __syncthreads();                 // gates visible (sync 1)

        // C. pre loads (issued last iter) now required
        asm volatile("s_waitcnt vmcnt(0)" ::: "memory");
        __builtin_amdgcn_sched_barrier(0);

        // D. elementwise update (fast transcendentals)
        const float* grow = Gl + b * GLS + hcp;
        const float2 g_f = *(const float2*)(grow);
        const float2 g_i = *(const float2*)(grow + 32);
        const float2 g_g = *(const float2*)(grow + 64);
        const float2 g_o = *(const float2*)(grow + 96);
        const float f0 = fsigm(g_f.x + pf.x), f1 = fsigm(g_f.y + pf.y);
        const float i0 = fsigm(g_i.x + pi.x), i1 = fsigm(g_i.y + pi.y);
        const float g0 = ftanh(g_g.x + pg.x), g1 = ftanh(g_g.y + pg.y);
        const float o0 = fsigm(g_o.x + po.x), o1 = fsigm(g_o.y + po.y);
        cv.x = f0 * cv.x + i0 * g0;
        cv.y = f1 * cv.y + i1 * g1;
        const float hn0 = o0 * ftanh(cv.x);
        const float hn1 = o1 * ftanh(cv.y);

        // E. stores (asm): outs dwordx2 plain, h dword sc1
        {
            float* optr = outs + ((size_t)gt << 14) + (b << 9) + col;
            f32x2 ov; ov.x = hn0; ov.y = hn1;
            asm volatile("global_store_dwordx2 %0, %1, off" :: "v"(optr), "v"(ov) : "memory");
            unsigned* hdst = (unsigned*)hbuf + (((gt + 1) & 1) << 13) + (b << 8) + (col >> 1);
            const unsigned pk = pack2(hn0, hn1);
            asm volatile("global_store_dword %0, %1, off sc1" :: "v"(hdst), "v"(pk) : "memory");
        }
        if (gt == T_STEPS - 1) {
            *(float2*)(hf + (b << 9) + col) = make_float2(hn0, hn1);
            *(float2*)(cf + (b << 9) + col) = make_float2(cv.x, cv.y);
            break;                              // no final barrier needed
        }

        // G. issue pre prefetch for t+1 (after the stores, so counted wait
        //    below covers stores only)
        {
            const int tn = (t + 1 < TC) ? t + 1 : t;
            const float* prn = pre + ((size_t)tn * BATCH + b) * G4 + col;
            asm volatile("global_load_dwordx2 %0, %1, off" : "=v"(pf) : "v"(prn) : "memory");
            asm volatile("global_load_dwordx2 %0, %1, off" : "=v"(pi) : "v"(prn + 512) : "memory");
            asm volatile("global_load_dwordx2 %0, %1, off" : "=v"(pg) : "v"(prn + 1024) : "memory");
            asm volatile("global_load_dwordx2 %0, %1, off" : "=v"(po) : "v"(prn + 1536) : "memory");
        }
        // H. drain the 2 stores only (4 loads may remain outstanding)
        asm volatile("s_waitcnt vmcnt(4)" ::: "memory");

        // I/J/K. grid barrier: contention-free arrival, 16-lane tight poll
        __syncthreads();                 // (sync 2) all waves' stores drained
        if (tid == 0)
            atomicAdd(flags + (g << 4), 1u);    // slot value = global steps done
        if (tid < 16) {
            unsigned* slot = flags + (tid << 4);
            const unsigned tgt = (unsigned)(gt + 1);
            for (;;) {
                unsigned vb;
                asm volatile("global_load_dword %0, %1, off sc1\n\ts_waitcnt vmcnt(0)"
                             : "=v"(vb) : "v"(slot) : "memory");
                if (vb >= tgt) break;
            }
        }
        __syncthreads();                 // (sync 3) barrier passed

        // L. stage h(gt+1) -> Hl (IC-coherent)
        {
            const unsigned short* hsrc = hbuf + (((gt + 1) & 1) << 14) + (w << 9) + (l << 3);
            u32x4 v0, v1, v2, v3;
            ld4x_ic(hsrc, hsrc + 4096, hsrc + 8192, hsrc + 12288, v0, v1, v2, v3);
            char* hd = Hl + w * 1024 + ((l << 4) ^ (w << 4));
            *(u32x4*)hd = v0; *(u32x4*)(hd + 8192) = v1;
            *(u32x4*)(hd + 16384) = v2; *(u32x4*)(hd + 24576) = v3;
        }
        __syncthreads();                 // (sync 4) Hl ready
    }

    cout[(b << 9) + col]     = cv.x;
    cout[(b << 9) + col + 1] = cv.y;
}

// ---------------------------------------------------------------------------
// Minimal fallback (tiny ws): 2048 step launches, fp32, x folded in.
// ---------------------------------------------------------------------------
__global__ __launch_bounds__(256) void lstm_step(const float* __restrict__ x_t,
                                                 const float* __restrict__ h_prev,
                                                 const float* __restrict__ W,
                                                 const float* __restrict__ bias,
                                                 const float* __restrict__ c_in,
                                                 float* __restrict__ c_out,
                                                 float* __restrict__ h_out,
                                                 float* __restrict__ hf,
                                                 float* __restrict__ cf, int last) {
    const int tid = threadIdx.x;
    const int hcc = tid & 7, b = tid >> 3;
    const int col = blockIdx.x * 8 + hcc;
    float a0 = bias[col], a1 = bias[col + 512], a2 = bias[col + 1024], a3 = bias[col + 1536];
    const float* xr = x_t + (size_t)b * IN_DIM;
    const float* hr = h_prev + (size_t)b * H_DIM;
    for (int k = 0; k < IN_DIM; ++k) {
        const float v = xr[k];
        const float* wk = &W[(size_t)k * G4 + col];
        a0 += v * wk[0]; a1 += v * wk[512]; a2 += v * wk[1024]; a3 += v * wk[1536];
    }
    for (int k = 0; k < H_DIM; ++k) {
        const float v = hr[k];
        const float* wk = &W[(size_t)(512 + k) * G4 + col];
        a0 += v * wk[0]; a1 += v * wk[512]; a2 += v * wk[1024]; a3 += v * wk[1536];
    }
    const float cn = sigm(a0) * c_in[(size_t)b * H_DIM + col] + sigm(a1) * tanhf(a2);
    const float hn = sigm(a3) * tanhf(cn);
    c_out[(size_t)b * H_DIM + col] = cn;
    h_out[(size_t)b * H_DIM + col] = hn;
    if (last) { hf[(size_t)b * H_DIM + col] = hn; cf[(size_t)b * H_DIM + col] = cn; }
}

extern "C" void kernel_launch(void* const* d_in, const int* in_sizes, int n_in,
                              void* d_out, int out_size, void* d_ws, size_t ws_size,
                              hipStream_t stream) {
    const float* x    = (const float*)d_in[0];
    const float* h0   = (const float*)d_in[1];
    const float* c0   = (const float*)d_in[2];
    const float* W    = (const float*)d_in[3];
    const float* bias = (const float*)d_in[4];

    float* outs = (float*)d_out;
    float* hf   = outs + (size_t)T_STEPS * BATCH * H_DIM;
    float* cf   = hf + BATCH * H_DIM;

    // PROVEN-FIT layout (ran in rounds 3/4/8): 138,481,664 bytes total.
    const size_t OFF_WT = 134217728ull;            // pre chunk: 128 MB @ 0
    const size_t OFF_HB = OFF_WT + 4194304ull;     // Wt: 4 MB
    const size_t OFF_C  = OFF_HB + 65536ull;       // hbuf: 64 KB
    const size_t OFF_FL = OFF_C + 65536ull;        // c: 64 KB
    const size_t NEED   = OFF_FL + 4096ull;

    if (ws_size >= NEED) {
        float* pre          = (float*)d_ws;
        unsigned short* Wt  = (unsigned short*)((char*)d_ws + OFF_WT);
        unsigned short* hb  = (unsigned short*)((char*)d_ws + OFF_HB);
        float* c_ws         = (float*)((char*)d_ws + OFF_C);
        unsigned int* flags = (unsigned int*)((char*)d_ws + OFF_FL);

        hipMemsetAsync(flags, 0, 4096, stream);
        wt_kernel<<<dim3(64, 32), 256, 0, stream>>>(W, Wt);
        init_h<<<64, 256, 0, stream>>>(h0, hb);
        for (int k = 0; k < NCHUNK; ++k) {
            xw_mfma<<<dim3(32, TC * BATCH / 64), 256, 0, stream>>>(
                x + (size_t)k * TC * BATCH * IN_DIM, Wt, bias, pre);
            lstm_scan<<<NWG, NTHR, 0, stream>>>(
                Wt, pre, (k == 0) ? c0 : c_ws, c_ws, hb, outs, hf, cf, flags, k * TC);
        }
    } else {
        float* c_ws = (float*)d_ws;
        for (int t = 0; t < T_STEPS; ++t) {
            const float* hp = t ? outs + (size_t)(t - 1) * BATCH * H_DIM : h0;
            const float* ci = t ? c_ws : c0;
            lstm_step<<<64, 256, 0, stream>>>(x + (size_t)t * BATCH * IN_DIM,
                                              hp, W, bias, ci, c_ws,
                                              outs + (size_t)t * BATCH * H_DIM,
                                              hf, cf, (t == T_STEPS - 1) ? 1 : 0);
        }
    }
}